// Round 9
// baseline (155.687 us; speedup 1.0000x reference)
//
#include <hip/hip_runtime.h>
#include <hip/hip_bf16.h>
#include <cstdint>

// Problem constants
#define NB   32      // batch
#define NC   256     // z channels
#define NE   128     // embed dim
#define NS   256     // H*W pixels per batch
#define NV   4096    // vocab
#define NP   8192    // total pixels
#define NSPLIT 8     // vocab splits (512 codes each)

typedef unsigned short ushort_t;
typedef __attribute__((ext_vector_type(8))) short bf16x8;
typedef __attribute__((ext_vector_type(8))) unsigned short us8;
typedef __attribute__((ext_vector_type(4))) float f32x4;

__device__ __forceinline__ float bf2f(ushort_t u) {
    union { unsigned int i; float f; } x; x.i = ((unsigned int)u) << 16; return x.f;
}
__device__ __forceinline__ ushort_t f2bf(float f) {
    __hip_bfloat16 h = __float2bfloat16(f);
    ushort_t u; __builtin_memcpy(&u, &h, 2); return u;
}
__device__ __forceinline__ unsigned asu(float f) { unsigned u; __builtin_memcpy(&u,&f,4); return u; }
__device__ __forceinline__ float    asf(unsigned u) { float f; __builtin_memcpy(&f,&u,4); return f; }

// ---------------------------------------------------------------------------
// K1 (fused, validated round 8):
//  bx<8  -> pre_conv: z = pre_w @ z_e + pre_b. 1024 blocks; LDS weights;
//           k split 4 ways across waves; LDS partial-sum reduction.
//  bx==8 -> pack emb hi-bf16 into Bpack (MFMA B-frag order) + cnorm.
// Bpack (ushort units): [(G*4 + ks)*512 + L*8 + j],
//   element = emb[code = G*16 + (L&15)][k = ks*32 + (L>>4)*8 + j]
// ---------------------------------------------------------------------------
__global__ __launch_bounds__(256) void pre_conv_pack(
    const float* __restrict__ z_e, const float* __restrict__ pre_w,
    const float* __restrict__ pre_b, const float* __restrict__ emb,
    float* __restrict__ out_z, ushort_t* __restrict__ Bpack,
    float* __restrict__ cnorm)
{
    __shared__ __align__(16) float wtile[16 * 256];   // 16 KB
    __shared__ __align__(16) float part[4 * 16 * 64]; // 16 KB

    const int t = threadIdx.x;

    if (blockIdx.x == 8) {   // ---- pack role
        const int v     = (blockIdx.y * 4 + blockIdx.z) * 32 + (t >> 3);
        const int chunk = t & 7;
        const float4* rp = (const float4*)(emb + (size_t)v * NE + chunk * 16);
        float4 x0 = rp[0], x1 = rp[1], x2 = rp[2], x3 = rp[3];
        float xs[16] = { x0.x, x0.y, x0.z, x0.w, x1.x, x1.y, x1.z, x1.w,
                         x2.x, x2.y, x2.z, x2.w, x3.x, x3.y, x3.z, x3.w };
        us8 h0, h1;
        float nn = 0.f;
#pragma unroll
        for (int j = 0; j < 8; j++) {
            nn = fmaf(xs[j], xs[j], nn);
            h0[j] = f2bf(xs[j]);
        }
#pragma unroll
        for (int j = 0; j < 8; j++) {
            nn = fmaf(xs[8 + j], xs[8 + j], nn);
            h1[j] = f2bf(xs[8 + j]);
        }
        nn += __shfl_xor(nn, 1);
        nn += __shfl_xor(nn, 2);
        nn += __shfl_xor(nn, 4);
        if (chunk == 0) cnorm[v] = 0.5f * nn;

        const int G  = v >> 4;
        const int ks = chunk >> 1;
        const int q0 = (chunk & 1) * 2;
        const int L0 = (v & 15) | (q0 << 4);
        const int L1 = (v & 15) | ((q0 + 1) << 4);
        *(us8*)(Bpack + ((size_t)G * 4 + ks) * 512 + L0 * 8) = h0;
        *(us8*)(Bpack + ((size_t)G * 4 + ks) * 512 + L1 * 8) = h1;
        return;
    }

    // ---- pre_conv role
    const int e0 = blockIdx.x * 16;
    const int b  = blockIdx.y;
    const int s0 = blockIdx.z * 64;

    for (int idx = t; idx < 16 * 256; idx += 256)
        wtile[idx] = pre_w[(e0 + (idx >> 8)) * 256 + (idx & 255)];
    __syncthreads();

    const int kq = t >> 6, sl = t & 63;
    float acc[16];
#pragma unroll
    for (int r = 0; r < 16; r++) acc[r] = 0.f;

    const float* zin = z_e + (size_t)(b * NC + kq * 64) * NS + s0 + sl;
    const int cb = kq * 64;
#pragma unroll 4
    for (int i = 0; i < 16; i++) {
        const int c = i * 4;
        float z0 = zin[(c + 0) * NS];
        float z1 = zin[(c + 1) * NS];
        float z2 = zin[(c + 2) * NS];
        float z3 = zin[(c + 3) * NS];
#pragma unroll
        for (int r = 0; r < 16; r++) {
            float4 w = *(const float4*)&wtile[r * 256 + cb + c];
            acc[r] = fmaf(z0, w.x, fmaf(z1, w.y, fmaf(z2, w.z, fmaf(z3, w.w, acc[r]))));
        }
    }
#pragma unroll
    for (int r = 0; r < 16; r++)
        part[(kq * 16 + r) * 64 + sl] = acc[r];
    __syncthreads();

    const int r4 = t >> 6, sl2 = t & 63;
#pragma unroll
    for (int j = 0; j < 4; j++) {
        const int r = j * 4 + r4;
        float v = pre_b[e0 + r]
                + part[(0 * 16 + r) * 64 + sl2]
                + part[(1 * 16 + r) * 64 + sl2]
                + part[(2 * 16 + r) * 64 + sl2]
                + part[(3 * 16 + r) * 64 + sl2];
        out_z[(size_t)(b * NE + e0 + r) * NS + s0 + sl2] = v;
    }
}

// ---------------------------------------------------------------------------
// K2: MFMA score filter (round-7/8 logic, register-slimmed: no manual B
// prefetch -> ~150 VGPR, fits LB(256,3) without spills). Single bf16 term;
// per-lane top-2 per 8-code slot; block top-4 per split -> pidx4.
// ---------------------------------------------------------------------------
__global__ __launch_bounds__(256, 3) void score_mfma(
    const float* __restrict__ z, const ushort_t* __restrict__ Bpack,
    const float* __restrict__ cnorm, int* __restrict__ pidx4)
{
    __shared__ __align__(16) char smraw[37376];
    float* As  = (float*)smraw;             // 64*132*4 = 33792 B (staging)
    float* r1  = (float*)smraw;             // 64*65*4  = 16640 B (reduction)
    float* r2  = (float*)(smraw + 16640);   // 16640 B
    float* t4b = (float*)(smraw + 33280);   // 4096 B

    const int t = threadIdx.x;
    const int wave = t >> 6, lane = t & 63;
    const int set = blockIdx.x;      // 0..127
    const int split = blockIdx.y;    // 0..7
    const int p0 = set * 64;
    const int b  = p0 >> 8;
    const int s0 = p0 & 255;

    for (int idx = t; idx < 64 * 128; idx += 256) {
        int k = idx >> 6, i = idx & 63;
        As[i * 132 + k] = z[(size_t)(b * NE + k) * NS + s0 + i];
    }
    __syncthreads();

    const int am = lane & 15, aq = lane >> 4;
    bf16x8 ah[4][4];
#pragma unroll
    for (int mt = 0; mt < 4; mt++)
#pragma unroll
        for (int ks = 0; ks < 4; ks++) {
            const unsigned* src = (const unsigned*)(As + (mt * 16 + am) * 132 + ks * 32 + aq * 8);
            union { unsigned u[4]; bf16x8 v; } pk;
#pragma unroll
            for (int pr = 0; pr < 4; pr++)
                pk.u[pr] = (src[2 * pr + 1] & 0xFFFF0000u) | (src[2 * pr] >> 16);
            ah[mt][ks] = pk.v;
        }
    __syncthreads();

    const int Gbase = split * 32 + wave * 8;
    float cn[8];
#pragma unroll
    for (int cgi = 0; cgi < 8; cgi++)
        cn[cgi] = cnorm[(Gbase + cgi) * 16 + am];

    float b1v[16], b2v[16];
#pragma unroll
    for (int i = 0; i < 16; i++) { b1v[i] = -1e30f; b2v[i] = -1e30f; }

    for (int cgi = 0; cgi < 8; cgi++) {
        const int G = Gbase + cgi;
        bf16x8 bh[4];
#pragma unroll
        for (int ks = 0; ks < 4; ks++)
            bh[ks] = *(const bf16x8*)(Bpack + ((size_t)G * 4 + ks) * 512 + lane * 8);

        f32x4 acc[4];
#pragma unroll
        for (int mt = 0; mt < 4; mt++) acc[mt] = (f32x4){0.f, 0.f, 0.f, 0.f};
#pragma unroll
        for (int ks = 0; ks < 4; ks++)
#pragma unroll
            for (int mt = 0; mt < 4; mt++)
                acc[mt] = __builtin_amdgcn_mfma_f32_16x16x32_bf16(ah[mt][ks], bh[ks], acc[mt], 0, 0, 0);

#pragma unroll
        for (int mt = 0; mt < 4; mt++)
#pragma unroll
            for (int reg = 0; reg < 4; reg++) {
                const int si = mt * 4 + reg;
                float sc = acc[mt][reg] - cn[cgi];
                float ev = asf((asu(sc) & ~7u) | (unsigned)cgi);
                b2v[si] = fmaxf(b2v[si], fminf(ev, b1v[si]));
                b1v[si] = fmaxf(b1v[si], ev);
            }
    }

    const int slot = wave * 16 + am;
#pragma unroll
    for (int mt = 0; mt < 4; mt++)
#pragma unroll
        for (int reg = 0; reg < 4; reg++) {
            int px = mt * 16 + aq * 4 + reg;
            r1[slot * 65 + px] = b1v[mt * 4 + reg];
            r2[slot * 65 + px] = b2v[mt * 4 + reg];
        }
    __syncthreads();

    {
        const int px = t >> 2, ch = t & 3;
        float t1 = -1e30f, t2 = -1e30f, t3 = -1e30f, t4 = -1e30f;
        for (int i = 0; i < 16; i++) {
            int sl = ch * 16 + i;
#pragma unroll
            for (int e = 0; e < 2; e++) {
                float raw = e ? r2[sl * 65 + px] : r1[sl * 65 + px];
                unsigned vb = asu(raw);
                float v = asf((vb & ~511u) | ((unsigned)sl << 3) | (vb & 7u));
                t4 = fmaxf(t4, fminf(v, t3));
                t3 = fmaxf(t3, fminf(v, t2));
                t2 = fmaxf(t2, fminf(v, t1));
                t1 = fmaxf(t1, v);
            }
        }
        float* dst = t4b + (px * 4 + ch) * 4;
        dst[0] = t1; dst[1] = t2; dst[2] = t3; dst[3] = t4;
    }
    __syncthreads();

    if (t < 64) {
        float u1 = -1e30f, u2 = -1e30f, u3 = -1e30f, u4 = -1e30f;
        for (int ch = 0; ch < 4; ch++) {
#pragma unroll
            for (int j = 0; j < 4; j++) {
                float v = t4b[(t * 4 + ch) * 4 + j];
                u4 = fmaxf(u4, fminf(v, u3));
                u3 = fmaxf(u3, fminf(v, u2));
                u2 = fmaxf(u2, fminf(v, u1));
                u1 = fmaxf(u1, v);
            }
        }
        const int p = p0 + t;
        float uu[4] = { u1, u2, u3, u4 };
#pragma unroll
        for (int j = 0; j < 4; j++) {
            unsigned bits = asu(uu[j]) & 511u;
            int w = (int)(bits >> 7), res = (int)((bits >> 3) & 15u), cg = (int)(bits & 7u);
            pidx4[((size_t)split * NP + p) * 4 + j] = split * 512 + (w * 8 + cg) * 16 + res;
        }
    }
}

// ---------------------------------------------------------------------------
// K3: fp32 rescore of the 32 candidates/px (round-4-validated numerics:
// score = fp32 dot - cnorm; noise ~3e-11 << top-2 gap ~7e-5), pick token
// (tie -> lowest idx == np.argmin), gather z_q = emb[token].
// 512 blocks x 16 px, 16 threads/px (2 candidates each), 4 parallel partials.
// ---------------------------------------------------------------------------
__global__ __launch_bounds__(256) void rescore_gather(
    const float* __restrict__ z, const float* __restrict__ emb,
    const float* __restrict__ cnorm, const int* __restrict__ pidx4,
    float* __restrict__ out_zq)
{
    __shared__ __align__(16) float zl[16 * 132];
    __shared__ float bsl[16 * 16];
    __shared__ int   bil[16 * 16];
    __shared__ int   tok[16];

    const int t  = threadIdx.x;
    const int p0 = blockIdx.x * 16;
    const int b  = p0 >> 8;
    const int s0 = p0 & 255;

    for (int idx = t; idx < 16 * 128; idx += 256) {
        int k = idx >> 4, i = idx & 15;
        zl[i * 132 + k] = z[(size_t)(b * NE + k) * NS + s0 + i];
    }
    __syncthreads();

    const int il = t >> 4;   // px local 0..15
    const int cc = t & 15;   // candidate pair 0..15
    const int p  = p0 + il;
    float bs = -1e30f; int bi = 0x7fffffff;
#pragma unroll
    for (int jj = 0; jj < 2; jj++) {
        int cand = cc * 2 + jj;              // 0..31
        int split = cand >> 2, slot = cand & 3;
        int idx = pidx4[((size_t)split * NP + p) * 4 + slot];
        const float* er = emb + (size_t)idx * NE;
        float d0 = 0.f, d1 = 0.f, d2 = 0.f, d3 = 0.f;
        for (int k = 0; k < NE; k += 4) {
            float4 e4 = *(const float4*)(er + k);
            d0 = fmaf(zl[il * 132 + k + 0], e4.x, d0);
            d1 = fmaf(zl[il * 132 + k + 1], e4.y, d1);
            d2 = fmaf(zl[il * 132 + k + 2], e4.z, d2);
            d3 = fmaf(zl[il * 132 + k + 3], e4.w, d3);
        }
        float sc = (d0 + d1) + (d2 + d3) - cnorm[idx];
        if (sc > bs || (sc == bs && idx < bi)) { bs = sc; bi = idx; }
    }
    bsl[il * 16 + cc] = bs;
    bil[il * 16 + cc] = bi;
    __syncthreads();

    if (t < 16) {
        float B = -1e30f; int I = 0x7fffffff;
        for (int c = 0; c < 16; c++) {
            float sc = bsl[t * 16 + c]; int ii = bil[t * 16 + c];
            if (sc > B || (sc == B && ii < I)) { B = sc; I = ii; }
        }
        tok[t] = I;
    }
    __syncthreads();

    for (int idx = t; idx < NE * 16; idx += 256) {
        int e = idx >> 4, i = idx & 15;
        out_zq[(size_t)(b * NE + e) * NS + s0 + i] = emb[(size_t)tok[i] * NE + e];
    }
}

// ---------------------------------------------------------------------------
// K4 (validated round 8): rec = post_w @ z_q + post_b. 2048 blocks; LDS
// weights; k split 4 ways; LDS reduction. Overwrites scratch region last.
// ---------------------------------------------------------------------------
__global__ __launch_bounds__(256) void post_conv(
    const float* __restrict__ zq, const float* __restrict__ post_w,
    const float* __restrict__ post_b, float* __restrict__ out_rec)
{
    __shared__ __align__(16) float wtile[16 * 128];   // 8 KB
    __shared__ __align__(16) float part[4 * 16 * 64]; // 16 KB

    const int t  = threadIdx.x;
    const int c0 = blockIdx.x * 16;
    const int b  = blockIdx.y;
    const int s0 = blockIdx.z * 64;

    for (int idx = t; idx < 16 * 128; idx += 256)
        wtile[idx] = post_w[(c0 + (idx >> 7)) * 128 + (idx & 127)];
    __syncthreads();

    const int kq = t >> 6, sl = t & 63;
    float acc[16];
#pragma unroll
    for (int r = 0; r < 16; r++) acc[r] = 0.f;

    const float* zin = zq + (size_t)(b * NE + kq * 32) * NS + s0 + sl;
    const int eb = kq * 32;
#pragma unroll 4
    for (int i = 0; i < 8; i++) {
        const int e = i * 4;
        float z0 = zin[(e + 0) * NS];
        float z1 = zin[(e + 1) * NS];
        float z2 = zin[(e + 2) * NS];
        float z3 = zin[(e + 3) * NS];
#pragma unroll
        for (int r = 0; r < 16; r++) {
            float4 w = *(const float4*)&wtile[r * 128 + eb + e];
            acc[r] = fmaf(z0, w.x, fmaf(z1, w.y, fmaf(z2, w.z, fmaf(z3, w.w, acc[r]))));
        }
    }
#pragma unroll
    for (int r = 0; r < 16; r++)
        part[(kq * 16 + r) * 64 + sl] = acc[r];
    __syncthreads();

    const int r4 = t >> 6, sl2 = t & 63;
#pragma unroll
    for (int j = 0; j < 4; j++) {
        const int r = j * 4 + r4;
        float v = post_b[c0 + r]
                + part[(0 * 16 + r) * 64 + sl2]
                + part[(1 * 16 + r) * 64 + sl2]
                + part[(2 * 16 + r) * 64 + sl2]
                + part[(3 * 16 + r) * 64 + sl2];
        out_rec[(size_t)(b * NC + c0 + r) * NS + s0 + sl2] = v;
    }
}

// ---------------------------------------------------------------------------
extern "C" void kernel_launch(void* const* d_in, const int* in_sizes, int n_in,
                              void* d_out, int out_size, void* d_ws, size_t ws_size,
                              hipStream_t stream)
{
    const float* z_e    = (const float*)d_in[0];
    const float* pre_w  = (const float*)d_in[1];
    const float* pre_b  = (const float*)d_in[2];
    const float* emb    = (const float*)d_in[3];
    const float* post_w = (const float*)d_in[4];
    const float* post_b = (const float*)d_in[5];

    // d_out: fp32 x 4194304 = (z 1048576 | z_q 1048576 | rec 2097152)
    float* out     = (float*)d_out;
    float* out_z   = out;
    float* out_zq  = out + 1048576;
    float* out_rec = out + 2097152;

    // Scratch: Bpack 1 MB + cnorm 16 KB + pidx4 1 MB. Primary: d_ws;
    // fallback (constant per session): rec-region head, consumed pre-K4.
    const size_t SZ_BPACK = (size_t)256 * 4 * 512 * 2;            // 1 MB
    const size_t SZ_CNORM = (size_t)NV * 4;                       // 16 KB
    const size_t SZ_PIDX4 = (size_t)NSPLIT * NP * 4 * 4;          // 1 MB
    const size_t NEED = SZ_BPACK + SZ_CNORM + SZ_PIDX4;
    char* scr = (ws_size >= NEED) ? (char*)d_ws : (char*)out_rec;
    ushort_t* Bpack = (ushort_t*)scr;
    float*    cnorm = (float*)(scr + SZ_BPACK);
    int*      pidx4 = (int*)(scr + SZ_BPACK + SZ_CNORM);

    pre_conv_pack <<<dim3(9, 32, 4),     256, 0, stream>>>(z_e, pre_w, pre_b, emb,
                                                           out_z, Bpack, cnorm);
    score_mfma    <<<dim3(128, NSPLIT),  256, 0, stream>>>(out_z, Bpack, cnorm, pidx4);
    rescore_gather<<<dim3(512),          256, 0, stream>>>(out_z, emb, cnorm, pidx4, out_zq);
    post_conv     <<<dim3(16, 32, 4),    256, 0, stream>>>(out_zq, post_w, post_b, out_rec);
}